// Round 4
// baseline (133.645 us; speedup 1.0000x reference)
//
#include <hip/hip_runtime.h>

#define RH 128
#define RW 128
#define CS 21    // src channels
#define IH 512
#define IW 512
#define NPIX (RH * RW)
#define P 13         // dy split factor
#define SPITCH 160   // padded src row pitch (floats): 12 zero | 128 | 20 zero
#define SCH (RH * SPITCH)   // per-channel stride = 20480
#define IPITCH 152   // padded im row pitch (float4): 12 reflect | 128 | 12 reflect

// ---------------- K1a: downsample src 512->128, planar zero-padded ----------------
// out[c][y][xp], xp in [0,160): data at xp-12 in [0,128), else 0
__global__ void downsample_src_kernel(const float* __restrict__ in, float* __restrict__ out) {
    int idx = blockIdx.x * blockDim.x + threadIdx.x;
    if (idx >= CS * RH * SPITCH) return;
    int xp = idx % SPITCH;
    int t = idx / SPITCH;
    int y = t % RH;
    int c = t / RH;
    int x = xp - 12;
    if (x < 0 || x >= RW) { out[idx] = 0.f; return; }

    float wy[8], wx[8];
    int jy[8], jx[8];
    float sy = 4.f * y + 1.5f, sx = 4.f * x + 1.5f;
    float wys = 0.f, wxs = 0.f;
#pragma unroll
    for (int k = 0; k < 8; ++k) {
        int j = 4 * y - 2 + k;
        float w = 1.f - fabsf(sy - (float)j) * 0.25f;
        if (j < 0 || j >= IH) { w = 0.f; j = 0; }
        jy[k] = j; wy[k] = w; wys += w;
        int j2 = 4 * x - 2 + k;
        float w2 = 1.f - fabsf(sx - (float)j2) * 0.25f;
        if (j2 < 0 || j2 >= IW) { w2 = 0.f; j2 = 0; }
        jx[k] = j2; wx[k] = w2; wxs += w2;
    }
    float inv = 1.f / (wys * wxs);
    float s = 0.f;
#pragma unroll
    for (int a = 0; a < 8; ++a) {
        const float* row = in + (size_t)(jy[a] * IW) * CS + c;
        float rs = 0.f;
#pragma unroll
        for (int b = 0; b < 8; ++b) rs += wx[b] * row[jx[b] * CS];
        s += wy[a] * rs;
    }
    out[idx] = s * inv;
}

// ---------------- K1b: downsample im 512->128, float4, horizontally reflect-padded ----------------
// out[y][xp] (float4), xp in [0,152): im_r(y, reflect(xp-12))
__global__ void downsample_im_kernel(const float* __restrict__ in, float4* __restrict__ out) {
    int idx = blockIdx.x * blockDim.x + threadIdx.x;
    if (idx >= RH * IPITCH) return;
    int xp = idx % IPITCH;
    int y = idx / IPITCH;
    int gx = xp - 12;
    gx = gx < 0 ? -gx : (gx > RW - 1 ? 2 * (RW - 1) - gx : gx);

    float wy[8], wx[8];
    int jy[8], jx[8];
    float sy = 4.f * y + 1.5f, sx = 4.f * gx + 1.5f;
    float wys = 0.f, wxs = 0.f;
#pragma unroll
    for (int k = 0; k < 8; ++k) {
        int j = 4 * y - 2 + k;
        float w = 1.f - fabsf(sy - (float)j) * 0.25f;
        if (j < 0 || j >= IH) { w = 0.f; j = 0; }
        jy[k] = j; wy[k] = w; wys += w;
        int j2 = 4 * gx - 2 + k;
        float w2 = 1.f - fabsf(sx - (float)j2) * 0.25f;
        if (j2 < 0 || j2 >= IW) { w2 = 0.f; j2 = 0; }
        jx[k] = j2; wx[k] = w2; wxs += w2;
    }
    float inv = 1.f / (wys * wxs);
    float s0 = 0.f, s1 = 0.f, s2 = 0.f;
#pragma unroll
    for (int a = 0; a < 8; ++a) {
        const float* row = in + (size_t)(jy[a] * IW) * 3;
        float r0 = 0.f, r1 = 0.f, r2 = 0.f;
#pragma unroll
        for (int b = 0; b < 8; ++b) {
            const float* pp = row + jx[b] * 3;
            r0 += wx[b] * pp[0];
            r1 += wx[b] * pp[1];
            r2 += wx[b] * pp[2];
        }
        s0 += wy[a] * r0; s1 += wy[a] * r1; s2 += wy[a] * r2;
    }
    out[idx] = make_float4(s0 * inv, s1 * inv, s2 * inv, 0.f);
}

// ---------------- K2: joint bilateral, planar padded src, P=13 dy split ----------------
__global__ __launch_bounds__(256) void bilateral_kernel(
        const float* __restrict__ srcP,   // [21][128][160] zero-padded
        const float4* __restrict__ im4P,  // [128][152] reflect-padded
        float* __restrict__ part) {       // [13][21][NPIX]
    int wid = (blockIdx.x << 2) + (threadIdx.x >> 6);   // 0..3327
    int lane = threadIdx.x & 63;
    int p = wid >> 8;                                   // 0..12
    int pxw = wid & 255;
    int h = pxw & 1;
    int y = pxw >> 1;
    int x = (h << 6) + lane;

    float4 ctr = im4P[y * IPITCH + x + 12];
    float acc[CS];
#pragma unroll
    for (int c = 0; c < CS; ++c) acc[c] = 0.f;

    for (int dy = p; dy < 25; dy += P) {
        int ry = y + dy - 12;
        if (ry < 0 || ry >= RH) continue;               // wave-uniform; src zero-pad
        float fdy = (float)(dy - 12);
        float gy = fdy * fdy;
        const float* srow = srcP + ry * SPITCH + x;     // + c*SCH + dx
        const float4* irow = im4P + ry * IPITCH + x;    // + dx
#pragma unroll 5
        for (int dx = 0; dx < 25; ++dx) {
            float4 q = irow[dx];
            float d0 = q.x - ctr.x, d1 = q.y - ctr.y, d2 = q.z - ctr.z;
            float fdx = (float)(dx - 12);
            float e = -(d0 * d0 + d1 * d1 + d2 * d2) * (1.f / 18.f)
                      - (gy + fdx * fdx) * (1.f / 128.f);
            float cw = __expf(e);
#pragma unroll
            for (int c = 0; c < CS; ++c)
                acc[c] = fmaf(cw, srow[c * SCH + dx], acc[c]);
        }
    }
    int pix = (y << 7) + x;
#pragma unroll
    for (int c = 0; c < CS; ++c)
        part[((size_t)(p * CS + c) << 14) + pix] = acc[c];
}

// ---------------- K2b: reduce partials ----------------
__global__ void reduce_kernel(const float* __restrict__ part, float* __restrict__ outr) {
    int t = blockIdx.x * blockDim.x + threadIdx.x;
    if (t >= CS * NPIX) return;
    int c = t >> 14;
    int pix = t & (NPIX - 1);
    float s = 0.f;
#pragma unroll
    for (int p = 0; p < P; ++p)
        s += part[((size_t)(p * CS + c) << 14) + pix];
    outr[(size_t)pix * CS + c] = s;
}

// ---------------- K3: bilinear upsample 128 -> 512 ----------------
__global__ void upsample_kernel(const float* __restrict__ inr, float* __restrict__ out, int total) {
    int idx = blockIdx.x * blockDim.x + threadIdx.x;
    if (idx >= total) return;
    int c = idx % CS;
    int t = idx / CS;
    int X = t % IW, Y = t / IW;
    float fy = 0.25f * (float)Y - 0.375f;
    float fx = 0.25f * (float)X - 0.375f;
    int y0 = (int)floorf(fy); float ty = fy - (float)y0;
    int x0 = (int)floorf(fx); float tx = fx - (float)x0;
    int y1 = y0 + 1, x1 = x0 + 1;
    y0 = min(max(y0, 0), RH - 1); y1 = min(max(y1, 0), RH - 1);
    x0 = min(max(x0, 0), RW - 1); x1 = min(max(x1, 0), RW - 1);
    float v00 = inr[(y0 * RW + x0) * CS + c], v01 = inr[(y0 * RW + x1) * CS + c];
    float v10 = inr[(y1 * RW + x0) * CS + c], v11 = inr[(y1 * RW + x1) * CS + c];
    float v0 = v00 + tx * (v01 - v00);
    float v1 = v10 + tx * (v11 - v10);
    out[idx] = v0 + ty * (v1 - v0);
}

extern "C" void kernel_launch(void* const* d_in, const int* in_sizes, int n_in,
                              void* d_out, int out_size, void* d_ws, size_t ws_size,
                              hipStream_t stream) {
    const float* src = (const float*)d_in[0];   // (1,512,512,21) f32
    const float* im  = (const float*)d_in[1];   // (1,512,512,3)  f32
    float* out = (float*)d_out;                 // (1,512,512,21) f32 = 22,020,096 B
    char* ws = (char*)d_ws;

    // big scratch lives in d_out (overwritten by K3 at the end, stream-ordered):
    float* part = out;                                  // [13][21][16384] = 17,891,328 B
    float* srcP = (float*)((char*)d_out + 17891328);    // [21][128][160] =  1,720,320 B (tot 19.6MB < 22.02MB)
    // small scratch in ws:
    float4* im4P = (float4*)(ws);                       // [128][152]     =    311,296 B
    float* out_r = (float*)(ws + 311296);               // [128][128][21] =  1,376,256 B

    int t1 = CS * RH * SPITCH;
    downsample_src_kernel<<<(t1 + 255) / 256, 256, 0, stream>>>(src, srcP);
    int t2 = RH * IPITCH;
    downsample_im_kernel<<<(t2 + 255) / 256, 256, 0, stream>>>(im, im4P);

    // 3328 waves = 832 blocks of 4 waves
    bilateral_kernel<<<832, 256, 0, stream>>>(srcP, im4P, part);

    int tr = CS * NPIX;
    reduce_kernel<<<(tr + 255) / 256, 256, 0, stream>>>(part, out_r);

    int t3 = IH * IW * CS;
    upsample_kernel<<<(t3 + 255) / 256, 256, 0, stream>>>(out_r, out, t3);
}

// Round 5
// 77.503 us; speedup vs baseline: 1.7244x; 1.7244x over previous
//
#include <hip/hip_runtime.h>

#define RH 128
#define RW 128
#define CS 21    // src channels
#define IH 512
#define IW 512
#define NPIX (RH * RW)
#define P 13         // dy split factor
#define SPITCH 160   // padded src row pitch (floats): 12 zero | 128 | 20 zero
#define SCH (RH * SPITCH)   // per-channel stride = 20480
#define IPITCH 152   // padded im row pitch (float4): 12 reflect | 128 | 12 reflect

// ---------------- K1a: downsample src 512->128, planar zero-padded ----------------
// out[c][y][xp]; c-fastest thread mapping so input reads are coalesced
// (consecutive lanes read consecutive channels of the same input pixel).
__global__ void downsample_src_kernel(const float* __restrict__ in, float* __restrict__ out) {
    int idx = blockIdx.x * blockDim.x + threadIdx.x;
    if (idx >= CS * RH * SPITCH) return;
    int c = idx % CS;
    int t = idx / CS;
    int xp = t % SPITCH;
    int y = t / SPITCH;
    size_t oidx = (size_t)c * SCH + y * SPITCH + xp;
    int x = xp - 12;
    if (x < 0 || x >= RW) { out[oidx] = 0.f; return; }

    float wy[8], wx[8];
    int jy[8], jx[8];
    float sy = 4.f * y + 1.5f, sx = 4.f * x + 1.5f;
    float wys = 0.f, wxs = 0.f;
#pragma unroll
    for (int k = 0; k < 8; ++k) {
        int j = 4 * y - 2 + k;
        float w = 1.f - fabsf(sy - (float)j) * 0.25f;
        if (j < 0 || j >= IH) { w = 0.f; j = 0; }
        jy[k] = j; wy[k] = w; wys += w;
        int j2 = 4 * x - 2 + k;
        float w2 = 1.f - fabsf(sx - (float)j2) * 0.25f;
        if (j2 < 0 || j2 >= IW) { w2 = 0.f; j2 = 0; }
        jx[k] = j2; wx[k] = w2; wxs += w2;
    }
    float inv = 1.f / (wys * wxs);
    float s = 0.f;
#pragma unroll
    for (int a = 0; a < 8; ++a) {
        const float* row = in + (size_t)(jy[a] * IW) * CS + c;
        float rs = 0.f;
#pragma unroll
        for (int b = 0; b < 8; ++b) rs += wx[b] * row[jx[b] * CS];
        s += wy[a] * rs;
    }
    out[oidx] = s * inv;
}

// ---------------- K1b: downsample im 512->128, float4, horizontally reflect-padded ----------------
__global__ void downsample_im_kernel(const float* __restrict__ in, float4* __restrict__ out) {
    int idx = blockIdx.x * blockDim.x + threadIdx.x;
    if (idx >= RH * IPITCH) return;
    int xp = idx % IPITCH;
    int y = idx / IPITCH;
    int gx = xp - 12;
    gx = gx < 0 ? -gx : (gx > RW - 1 ? 2 * (RW - 1) - gx : gx);

    float wy[8], wx[8];
    int jy[8], jx[8];
    float sy = 4.f * y + 1.5f, sx = 4.f * gx + 1.5f;
    float wys = 0.f, wxs = 0.f;
#pragma unroll
    for (int k = 0; k < 8; ++k) {
        int j = 4 * y - 2 + k;
        float w = 1.f - fabsf(sy - (float)j) * 0.25f;
        if (j < 0 || j >= IH) { w = 0.f; j = 0; }
        jy[k] = j; wy[k] = w; wys += w;
        int j2 = 4 * gx - 2 + k;
        float w2 = 1.f - fabsf(sx - (float)j2) * 0.25f;
        if (j2 < 0 || j2 >= IW) { w2 = 0.f; j2 = 0; }
        jx[k] = j2; wx[k] = w2; wxs += w2;
    }
    float inv = 1.f / (wys * wxs);
    float s0 = 0.f, s1 = 0.f, s2 = 0.f;
#pragma unroll
    for (int a = 0; a < 8; ++a) {
        const float* row = in + (size_t)(jy[a] * IW) * 3;
        float r0 = 0.f, r1 = 0.f, r2 = 0.f;
#pragma unroll
        for (int b = 0; b < 8; ++b) {
            const float* pp = row + jx[b] * 3;
            r0 += wx[b] * pp[0];
            r1 += wx[b] * pp[1];
            r2 += wx[b] * pp[2];
        }
        s0 += wy[a] * r0; s1 += wy[a] * r1; s2 += wy[a] * r2;
    }
    out[idx] = make_float4(s0 * inv, s1 * inv, s2 * inv, 0.f);
}

// ---------------- K2: joint bilateral, planar padded src, P=13 dy split ----------------
__global__ __launch_bounds__(256) void bilateral_kernel(
        const float* __restrict__ srcP,   // [21][128][160] zero-padded
        const float4* __restrict__ im4P,  // [128][152] reflect-padded
        float* __restrict__ part) {       // [13][21][NPIX]
    int wid = (blockIdx.x << 2) + (threadIdx.x >> 6);   // 0..3327
    int lane = threadIdx.x & 63;
    int p = wid >> 8;                                   // 0..12
    int pxw = wid & 255;
    int h = pxw & 1;
    int y = pxw >> 1;
    int x = (h << 6) + lane;

    float4 ctr = im4P[y * IPITCH + x + 12];
    float acc[CS];
#pragma unroll
    for (int c = 0; c < CS; ++c) acc[c] = 0.f;

    for (int dy = p; dy < 25; dy += P) {
        int ry = y + dy - 12;
        if (ry < 0 || ry >= RH) continue;               // wave-uniform; src zero-pad
        float fdy = (float)(dy - 12);
        float gy = fdy * fdy;
        const float* srow = srcP + ry * SPITCH + x;     // + c*SCH + dx
        const float4* irow = im4P + ry * IPITCH + x;    // + dx
#pragma unroll 5
        for (int dx = 0; dx < 25; ++dx) {
            float4 q = irow[dx];
            float d0 = q.x - ctr.x, d1 = q.y - ctr.y, d2 = q.z - ctr.z;
            float fdx = (float)(dx - 12);
            float e = -(d0 * d0 + d1 * d1 + d2 * d2) * (1.f / 18.f)
                      - (gy + fdx * fdx) * (1.f / 128.f);
            float cw = __expf(e);
#pragma unroll
            for (int c = 0; c < CS; ++c)
                acc[c] = fmaf(cw, srow[c * SCH + dx], acc[c]);
        }
    }
    int pix = (y << 7) + x;
#pragma unroll
    for (int c = 0; c < CS; ++c)
        part[((size_t)(p * CS + c) << 14) + pix] = acc[c];
}

// ---------------- K2b: reduce partials ----------------
__global__ void reduce_kernel(const float* __restrict__ part, float* __restrict__ outr) {
    int t = blockIdx.x * blockDim.x + threadIdx.x;
    if (t >= CS * NPIX) return;
    int c = t >> 14;
    int pix = t & (NPIX - 1);
    float s = 0.f;
#pragma unroll
    for (int p = 0; p < P; ++p)
        s += part[((size_t)(p * CS + c) << 14) + pix];
    outr[(size_t)pix * CS + c] = s;
}

// ---------------- K3: bilinear upsample 128 -> 512 ----------------
__global__ void upsample_kernel(const float* __restrict__ inr, float* __restrict__ out, int total) {
    int idx = blockIdx.x * blockDim.x + threadIdx.x;
    if (idx >= total) return;
    int c = idx % CS;
    int t = idx / CS;
    int X = t % IW, Y = t / IW;
    float fy = 0.25f * (float)Y - 0.375f;
    float fx = 0.25f * (float)X - 0.375f;
    int y0 = (int)floorf(fy); float ty = fy - (float)y0;
    int x0 = (int)floorf(fx); float tx = fx - (float)x0;
    int y1 = y0 + 1, x1 = x0 + 1;
    y0 = min(max(y0, 0), RH - 1); y1 = min(max(y1, 0), RH - 1);
    x0 = min(max(x0, 0), RW - 1); x1 = min(max(x1, 0), RW - 1);
    float v00 = inr[(y0 * RW + x0) * CS + c], v01 = inr[(y0 * RW + x1) * CS + c];
    float v10 = inr[(y1 * RW + x0) * CS + c], v11 = inr[(y1 * RW + x1) * CS + c];
    float v0 = v00 + tx * (v01 - v00);
    float v1 = v10 + tx * (v11 - v10);
    out[idx] = v0 + ty * (v1 - v0);
}

extern "C" void kernel_launch(void* const* d_in, const int* in_sizes, int n_in,
                              void* d_out, int out_size, void* d_ws, size_t ws_size,
                              hipStream_t stream) {
    const float* src = (const float*)d_in[0];   // (1,512,512,21) f32
    const float* im  = (const float*)d_in[1];   // (1,512,512,3)  f32
    float* out = (float*)d_out;                 // (1,512,512,21) f32 = 22,020,096 B
    char* ws = (char*)d_ws;

    // big scratch lives in d_out (overwritten by K3 at the end, stream-ordered):
    float* part = out;                                  // [13][21][16384] = 17,891,328 B
    float* srcP = (float*)((char*)d_out + 17891328);    // [21][128][160] =  1,720,320 B (tot 19.6MB < 22.02MB)
    // small scratch in ws:
    float4* im4P = (float4*)(ws);                       // [128][152]     =    311,296 B
    float* out_r = (float*)(ws + 311296);               // [128][128][21] =  1,376,256 B

    int t1 = CS * RH * SPITCH;
    downsample_src_kernel<<<(t1 + 255) / 256, 256, 0, stream>>>(src, srcP);
    int t2 = RH * IPITCH;
    downsample_im_kernel<<<(t2 + 255) / 256, 256, 0, stream>>>(im, im4P);

    // 3328 waves = 832 blocks of 4 waves
    bilateral_kernel<<<832, 256, 0, stream>>>(srcP, im4P, part);

    int tr = CS * NPIX;
    reduce_kernel<<<(tr + 255) / 256, 256, 0, stream>>>(part, out_r);

    int t3 = IH * IW * CS;
    upsample_kernel<<<(t3 + 255) / 256, 256, 0, stream>>>(out_r, out, t3);
}